// Round 6
// baseline (185.230 us; speedup 1.0000x reference)
//
#include <hip/hip_runtime.h>
#include <hip/hip_bf16.h>
#include <stdint.h>

#define B_  4
#define S_  2048
#define D_  1024
#define H_  16
#define HD_ 64
#define LOG2E 1.44269504088896f

typedef unsigned short u16;
typedef short bf16x8 __attribute__((ext_vector_type(8)));
typedef float f32x4 __attribute__((ext_vector_type(4)));

static __device__ __forceinline__ u16 f2bf(float f) {
    union { float f; uint32_t u; } v; v.f = f;
    return (u16)((v.u + 0x7FFF + ((v.u >> 16) & 1)) >> 16);
}

static __device__ __forceinline__ uint32_t cvt_pk_bf16(float lo, float hi) {
    uint32_t r;
    asm("v_cvt_pk_bf16_f32 %0, %1, %2" : "=v"(r) : "v"(lo), "v"(hi));
    return r;
}

// Swizzled 16B LDS read from a tile with 128B rows. slot = logical 16B column (0..7).
static __device__ __forceinline__ bf16x8 rd_swz(const u16* base, int row, int slot) {
    return *(const bf16x8*)((const char*)base + row * 128 + ((slot ^ (row & 7)) << 4));
}

// global -> LDS direct copy (16B/lane) of one 8-row x 128B chunk; inverse swizzle
// on the GLOBAL side (linear LDS dest + pre-swizzled source + swizzled reads).
static __device__ __forceinline__ void gll_swz(const u16* grow0, size_t stride,
                                               u16* lds_chunk, int lane) {
    const int r = lane >> 3;
    const int slot = (lane & 7) ^ r;
    const u16* g = grow0 + (size_t)r * stride + slot * 8;
    __builtin_amdgcn_global_load_lds(
        (const __attribute__((address_space(1))) uint32_t*)g,
        (__attribute__((address_space(3))) uint32_t*)lds_chunk, 16, 0, 0);
}

// ---------------- weight transpose + bf16 convert: Wt[n][k] = bf16(W[k][n]) ----------------
__global__ __launch_bounds__(256) void wtrans(
    const float* __restrict__ W0, const float* __restrict__ W1, const float* __restrict__ W2,
    u16* __restrict__ T0, u16* __restrict__ T1, u16* __restrict__ T2)
{
    const float* W = blockIdx.z == 0 ? W0 : (blockIdx.z == 1 ? W1 : W2);
    u16* T       = blockIdx.z == 0 ? T0 : (blockIdx.z == 1 ? T1 : T2);
    __shared__ float t[32][33];
    const int n0 = blockIdx.x * 32, k0 = blockIdx.y * 32;
    const int tx = threadIdx.x, ty = threadIdx.y;
#pragma unroll
    for (int i = 0; i < 4; ++i)
        t[ty + i * 8][tx] = W[(size_t)(k0 + ty + i * 8) * D_ + n0 + tx];
    __syncthreads();
#pragma unroll
    for (int i = 0; i < 4; ++i)
        T[(size_t)(n0 + ty + i * 8) * D_ + k0 + tx] = f2bf(t[tx][ty + i * 8]);
}

// ---------------- projection GEMM: Y = X @ Wt^T + b ----------------
// MODE 0: Q -> (B,H,S,HD) bf16, scaled by 0.125*log2(e)  (softmax in base-2 domain)
// MODE 1: K -> (B,H,S,HD) bf16
// MODE 2: V -> (B,H,HD,S) bf16, kv permuted within each 64-block (rho) for b128 PV reads
template <int MODE>
__global__ __launch_bounds__(256) void proj_gemm(
    const float* __restrict__ X, const u16* __restrict__ Wt,
    const float* __restrict__ bias, u16* __restrict__ out)
{
    __shared__ __align__(16) u16 lA[128 * 64];
    __shared__ __align__(16) u16 lB[128 * 64];
    const int tid = threadIdx.x;
    const int m0 = blockIdx.x * 128, n0 = blockIdx.y * 128;
    const int w = tid >> 6, lane = tid & 63;
    const int lr = lane & 15, lg = lane >> 4;
    const int wr = (w >> 1) * 64, wc = (w & 1) * 64;

    f32x4 acc[4][4] = {};

    for (int k0 = 0; k0 < D_; k0 += 64) {
        __syncthreads();
#pragma unroll
        for (int i = 0; i < 4; ++i) {
            const int c = w * 4 + i;
            gll_swz(Wt + (size_t)(n0 + c * 8) * D_ + k0, D_, &lB[c * 512], lane);
        }
#pragma unroll
        for (int i = 0; i < 8; ++i) {
            const int lin = i * 1024 + tid * 4;
            const int r = lin >> 6, c = lin & 63;
            const float4 v = *(const float4*)(X + (size_t)(m0 + r) * D_ + k0 + c);
            uint2 pk;
            pk.x = (uint32_t)f2bf(v.x) | ((uint32_t)f2bf(v.y) << 16);
            pk.y = (uint32_t)f2bf(v.z) | ((uint32_t)f2bf(v.w) << 16);
            const int phys = r * 128 + (((c >> 3) ^ (r & 7)) << 4) + ((c & 7) << 1);
            *(uint2*)((char*)lA + phys) = pk;
        }
        __syncthreads();
#pragma unroll
        for (int kk = 0; kk < 64; kk += 32) {
            bf16x8 af[4], bfr[4];
#pragma unroll
            for (int m = 0; m < 4; ++m)
                af[m] = rd_swz(lA, wr + m * 16 + lr, (kk >> 3) + lg);
#pragma unroll
            for (int n = 0; n < 4; ++n)
                bfr[n] = rd_swz(lB, wc + n * 16 + lr, (kk >> 3) + lg);
#pragma unroll
            for (int m = 0; m < 4; ++m)
#pragma unroll
                for (int n = 0; n < 4; ++n)
                    acc[m][n] = __builtin_amdgcn_mfma_f32_16x16x32_bf16(af[m], bfr[n], acc[m][n], 0, 0, 0);
        }
    }
#pragma unroll
    for (int m = 0; m < 4; ++m)
#pragma unroll
        for (int n = 0; n < 4; ++n)
#pragma unroll
            for (int j = 0; j < 4; ++j) {
                const int gm = m0 + wr + m * 16 + lg * 4 + j;
                const int gn = n0 + wc + n * 16 + lr;
                float y = acc[m][n][j] + bias[gn];
                if (MODE == 0) y *= 0.125f * LOG2E;
                const int bb = gm >> 11, s = gm & (S_ - 1);
                const int h = gn >> 6, hd = gn & 63;
                size_t off;
                if (MODE < 2) off = (((size_t)bb * H_ + h) * S_ + s) * HD_ + hd;
                else {
                    // rho: position p holds kv = 32m+16(jj>>2)+4lg+(jj&3); store kv s at p
                    const int s6 = s & 63;
                    const int sp = (s & ~63) | (s6 & 0x20) | ((s6 & 0xC) << 1) |
                                   ((s6 & 0x10) >> 2) | (s6 & 3);
                    off = (((size_t)bb * H_ + h) * HD_ + hd) * S_ + sp;
                }
                out[off] = f2bf(y);
            }
}

// ---------------- causal flash attention ----------------
// 1024 one-q-tile blocks (QBLK=128, 8 waves); exactly all-resident at 4 blocks/CU.
// qi map: nibble-table permutation T (aligned 4-groups sum to 30, pairs to 15),
// indexed by s15^round. Bijective per head (round fixed per bh, s15 spans 0..15);
// {s15^round} spans one aligned 4-group under both round-robin and consecutive
// block->CU assignments -> every CU's 4-block work sum == exact average.
// Double-buffered K/V staging (T3 2-phase): issue tile t+1's global_load_lds,
// compute tile t, single drain+barrier per tile.
// Swapped QK^T: lane owns q-row lr; softmax in-register (xor16/32 shfls only).
// PV: A-frag = lane's own cvt_pk words (pi == rho V layout), B-frag = one swizzled
// ds_read_b128. Defer-max (T13, THR=8): skip O-rescale while max grows <= 8.
__global__ __launch_bounds__(512) void attn_kernel(
    const u16* __restrict__ qb, const u16* __restrict__ kb,
    const u16* __restrict__ vtb, float* __restrict__ out)
{
    const int bid = blockIdx.x;
    const int slot = bid & 255, round = bid >> 8;
    const int s15 = slot & 15;
    // T = {15,0,8,7, 13,2,10,5, 14,1,9,6, 12,3,11,4} packed little-nibble-first
    const int qi = (int)((0x4B3C691E5A2D780FULL >> (((s15 ^ round) & 15) * 4)) & 15);
    const int bh = (round << 4) | (slot >> 4);
    const int b = bh >> 4, h = bh & 15;
    const int tid = threadIdx.x;
    const int w = tid >> 6, lane = tid & 63;
    const int lr = lane & 15, lg = lane >> 4;

    __shared__ __align__(16) u16 lK[2][64 * 64];  // [buf][kv][d], swizzled
    __shared__ __align__(16) u16 lV[2][64 * 64];  // [buf][d][kv-rho], swizzled

    const size_t kbase = (size_t)bh * S_ * HD_;
    const size_t vbase = (size_t)bh * HD_ * S_;

    const int q0 = qi * 128;
    const int qrow = q0 + w * 16 + lr;
    const size_t qoff = ((size_t)bh * S_ + qrow) * HD_;
    const bf16x8 qf0 = *(const bf16x8*)(qb + qoff + lg * 8);
    const bf16x8 qf1 = *(const bf16x8*)(qb + qoff + 32 + lg * 8);

    f32x4 oacc[4] = {};
    float m_run = -1e30f, l_run = 0.f;

    const int tmax = 2 * qi + 1;

    // prologue: stage tile 0 into buf 0 (wave w stages K-chunk w, V-chunk w)
    gll_swz(kb + kbase + (size_t)(w * 8) * HD_, HD_, &lK[0][w * 512], lane);
    gll_swz(vtb + vbase + (size_t)(w * 8) * S_, S_, &lV[0][w * 512], lane);
    __syncthreads();  // compiler drains vmcnt before barrier

    for (int t = 0; t <= tmax; ++t) {
        const int cur = t & 1;
        // issue next tile's staging loads (stay in flight across this tile's compute)
        if (t < tmax) {
            const int kv1 = (t + 1) * 64;
            gll_swz(kb + kbase + (size_t)(kv1 + w * 8) * HD_, HD_, &lK[cur ^ 1][w * 512], lane);
            gll_swz(vtb + vbase + (size_t)(w * 8) * S_ + kv1, S_, &lV[cur ^ 1][w * 512], lane);
        }

        // last tile: waves 0-3 are fully above the diagonal -> skip compute
        if (!(t == tmax && w < 4)) {
            const int kv0 = t * 64;
            const u16* lKc = &lK[cur][0];
            const u16* lVc = &lV[cur][0];

            // S^T = K Q^T (swapped operands)
            f32x4 sacc[4];
            __builtin_amdgcn_s_setprio(1);
#pragma unroll
            for (int n = 0; n < 4; ++n) {
                const bf16x8 k0f = rd_swz(lKc, n * 16 + lr, lg);
                const bf16x8 k1f = rd_swz(lKc, n * 16 + lr, 4 + lg);
                f32x4 z = {};
                z = __builtin_amdgcn_mfma_f32_16x16x32_bf16(k0f, qf0, z, 0, 0, 0);
                z = __builtin_amdgcn_mfma_f32_16x16x32_bf16(k1f, qf1, z, 0, 0, 0);
                sacc[n] = z;
            }
            __builtin_amdgcn_s_setprio(0);

            // causal mask (only the last two tiles can straddle the diagonal)
            if (t >= tmax - 1) {
#pragma unroll
                for (int n = 0; n < 4; ++n)
#pragma unroll
                    for (int j = 0; j < 4; ++j)
                        if (kv0 + n * 16 + lg * 4 + j > qrow) sacc[n][j] = -1e30f;
            }

            // in-register softmax for q-row lr (base-2; log2e folded into Q scale)
            float rm = -1e30f;
#pragma unroll
            for (int n = 0; n < 4; ++n)
#pragma unroll
                for (int j = 0; j < 4; ++j) rm = fmaxf(rm, sacc[n][j]);
            rm = fmaxf(rm, __shfl_xor(rm, 16));
            rm = fmaxf(rm, __shfl_xor(rm, 32));

            // defer-max: keep old max unless it grew by > 8 (P bounded by 2^8)
            const bool up = rm > m_run + 8.0f;
            const float mn = up ? rm : m_run;
            const float alpha = up ? exp2f(m_run - rm) : 1.0f;
            m_run = mn;

            float rs = 0.f;
#pragma unroll
            for (int n = 0; n < 4; ++n)
#pragma unroll
                for (int j = 0; j < 4; ++j) {
                    const float p = exp2f(sacc[n][j] - mn);
                    sacc[n][j] = p;
                    rs += p;
                }
            rs += __shfl_xor(rs, 16);
            rs += __shfl_xor(rs, 32);
            l_run = l_run * alpha + rs;

            // pack P to bf16 words: pw[n][jh] = (p at kv 16n+4lg+2jh, +1)
            uint32_t pw[4][2];
#pragma unroll
            for (int n = 0; n < 4; ++n)
#pragma unroll
                for (int jh = 0; jh < 2; ++jh)
                    pw[n][jh] = cvt_pk_bf16(sacc[n][2 * jh], sacc[n][2 * jh + 1]);

            // O-rescale only when some lane's max actually moved
            if (__any(up)) {
#pragma unroll
                for (int j = 0; j < 4; ++j) {
                    const float a = __shfl(alpha, lg * 4 + j);
#pragma unroll
                    for (int n = 0; n < 4; ++n) oacc[n][j] *= a;
                }
            }

            // PV: O[q][d] += P V; rho V layout makes B-frag one b128 at slot 4m+lg
            __builtin_amdgcn_s_setprio(1);
#pragma unroll
            for (int n = 0; n < 4; ++n) {
                const int row = n * 16 + lr;
#pragma unroll
                for (int m = 0; m < 2; ++m) {
                    const bf16x8 vf = rd_swz(lVc, row, 4 * m + lg);
                    union { uint32_t u[4]; bf16x8 v; } af;
                    af.u[0] = pw[2 * m][0]; af.u[1] = pw[2 * m][1];
                    af.u[2] = pw[2 * m + 1][0]; af.u[3] = pw[2 * m + 1][1];
                    oacc[n] = __builtin_amdgcn_mfma_f32_16x16x32_bf16(af.v, vf, oacc[n], 0, 0, 0);
                }
            }
            __builtin_amdgcn_s_setprio(0);
        }

        __syncthreads();  // drains the t+1 stage + guards buffer reuse
    }

    // epilogue
    const float inv = 1.f / l_run;
#pragma unroll
    for (int j = 0; j < 4; ++j) {
        const float iv = __shfl(inv, lg * 4 + j);
        const int row = q0 + w * 16 + lg * 4 + j;
#pragma unroll
        for (int n = 0; n < 4; ++n)
            out[((size_t)b * S_ + row) * D_ + h * HD_ + n * 16 + lr] = oacc[n][j] * iv;
    }
}

extern "C" void kernel_launch(void* const* d_in, const int* in_sizes, int n_in,
                              void* d_out, int out_size, void* d_ws, size_t ws_size,
                              hipStream_t stream) {
    const float* Q  = (const float*)d_in[0];
    const float* K  = (const float*)d_in[1];
    const float* V  = (const float*)d_in[2];
    const float* Wq = (const float*)d_in[3];
    const float* bq = (const float*)d_in[4];
    const float* Wk = (const float*)d_in[5];
    const float* bk = (const float*)d_in[6];
    const float* Wv = (const float*)d_in[7];
    const float* bv = (const float*)d_in[8];
    float* out = (float*)d_out;

    char* ws = (char*)d_ws;
    const size_t WT_BYTES  = (size_t)D_ * D_ * 2;
    const size_t QKV_BYTES = (size_t)B_ * S_ * D_ * 2;
    u16* Wtq = (u16*)(ws);
    u16* Wtk = (u16*)(ws + WT_BYTES);
    u16* Wtv = (u16*)(ws + 2 * WT_BYTES);
    u16* qb  = (u16*)(ws + 3 * WT_BYTES);
    u16* kb  = (u16*)(ws + 3 * WT_BYTES + QKV_BYTES);
    u16* vtb = (u16*)(ws + 3 * WT_BYTES + 2 * QKV_BYTES);

    wtrans<<<dim3(32, 32, 3), dim3(32, 8), 0, stream>>>(Wq, Wk, Wv, Wtq, Wtk, Wtv);
    proj_gemm<0><<<dim3(64, 8), dim3(256), 0, stream>>>(Q, Wtq, bq, qb);
    proj_gemm<1><<<dim3(64, 8), dim3(256), 0, stream>>>(K, Wtk, bk, kb);
    proj_gemm<2><<<dim3(64, 8), dim3(256), 0, stream>>>(V, Wtv, bv, vtb);
    attn_kernel<<<dim3(1024), dim3(512), 0, stream>>>(qb, kb, vtb, out);
}